// Round 17
// baseline (5298.320 us; speedup 1.0000x reference)
//
#include <hip/hip_runtime.h>
#include <math.h>

typedef double f64;
#define HDIM 64
#define NNODES 1024
#define NROWS 2048
#define RPB 4              // rows per block
#define NTHR 512           // 8 waves; wave w owns j-eighth w
#define WPB 8
#define TPW 8              // tiles per wave (16 j each)
#define NBLK (NROWS/RPB)   // 512 blocks -> 2 blocks/CU

__device__ __forceinline__ f64 wredsum64(f64 v){
#pragma unroll
  for(int o=32;o>0;o>>=1) v += __shfl_xor(v,o);
  return v;
}

// two-stage score, same op-order as the absmax-0 lineage
__device__ __forceinline__ void s_twostage64(const f64* ldsrow,
    const float* __restrict__ g_tr_w, const float* __restrict__ g_tr_b,
    const float* __restrict__ g_a, int h, f64& s_src, f64& s_dst){
  f64 t = (f64)g_tr_b[h];
  for(int c=0;c<HDIM;c++) t = fma(ldsrow[c], (f64)g_tr_w[c*HDIM+h], t);
  s_src = wredsum64(t*(f64)g_a[h]);
  s_dst = wredsum64(t*(f64)g_a[HDIM+h]);
}

// initial h1 + scores (1 wave/row) + folded f64 weight transpose
__global__ void k1(const float* __restrict__ x, const float* __restrict__ fw,
                   const float* __restrict__ fb,
                   const float* __restrict__ g_in_w, const float* __restrict__ g_in_b,
                   const float* __restrict__ g_tr_w, const float* __restrict__ g_tr_b,
                   const float* __restrict__ g_a,
                   const float* __restrict__ w_ih, const float* __restrict__ w_hh,
                   f64* __restrict__ w_ihT, f64* __restrict__ w_hhT,
                   f64* __restrict__ h1, f64* __restrict__ ssrc, f64* __restrict__ sdst){
  __shared__ f64 lx[4*64];
  __shared__ f64 lt[4*64];
  int wave = threadIdx.x >> 6, h = threadIdx.x & 63;
  int kk = blockIdx.x*256 + threadIdx.x;
  if(kk < 192*HDIM){
    int row=kk>>6, c=kk&63;
    w_ihT[c*192+row]=(f64)w_ih[kk];
    w_hhT[c*192+row]=(f64)w_hh[kk];
  }
  int r = blockIdx.x*4 + wave;
  int b = r >> 10, n = r & 1023;
  const float* xp = x + ((long)(b*32 + 0)*1024 + n)*6;
  f64 xh = (f64)fb[h];
#pragma unroll
  for(int f=0;f<6;f++) xh += (f64)xp[f]*(f64)fw[f*HDIM+h];
  lx[wave*64+h] = xh;
  __syncthreads();
  f64 a = (f64)g_in_b[h];
  for(int c=0;c<HDIM;c++) a += lx[wave*64+c]*(f64)g_in_w[c*HDIM+h];
  h1[(long)r*HDIM+h] = a;
  lt[wave*64+h] = a;
  __syncthreads();
  f64 s1,s2;
  s_twostage64(lt+wave*64, g_tr_w,g_tr_b,g_a, h, s1,s2);
  if(h==0){ ssrc[r]=s1; sdst[r]=s2; }
}

// One full GAT iteration per dispatch. 512 blocks x 512 thr (8 waves).
// Wave w owns j-eighth w (8 tiles of 16 j, rotated start), ALL 4 rows.
// Software pipeline per wave: ds_write(tile k) -> issue loads(tile k+1) ->
// weights(exp) -> s_waitcnt lgkmcnt(0) only -> FMA(tile k). Global loads
// stay in flight under the FMA. No block barriers in the agg loop.
// M=0: h1_out = agg + residual, + scores. M=1: GRU; next-h1+scores | FFN.
template<int M>
__global__ __launch_bounds__(NTHR) void k_att(
    const f64* __restrict__ h1_in, const f64* __restrict__ ss_in,
    const f64* __restrict__ sd_in,
    f64* __restrict__ h1_out, f64* __restrict__ ss_out, f64* __restrict__ sd_out,
    const float* __restrict__ g_tr_w, const float* __restrict__ g_tr_b,
    const float* __restrict__ g_a,
    const float* __restrict__ x, const float* __restrict__ fw, const float* __restrict__ fb,
    const f64* __restrict__ w_ihT, const f64* __restrict__ w_hhT,
    const float* __restrict__ b_ih, const float* __restrict__ b_hh,
    const float* __restrict__ g_in_w, const float* __restrict__ g_in_b,
    const float* __restrict__ ffn_w, const float* __restrict__ ffn_b,
    const float* __restrict__ ffn_ow, const float* __restrict__ ffn_ob,
    float* __restrict__ out, int step, int is_final)
{
  // pool layout (agg phase): [0..8191] 8x wave tile (16jx64h, 8KB each)
  //                          [8192..8703] 8x wave weights (64 each)
  // re-aliased after barrier: pacS [0..2047]=(q*4+r)*64+h ; pws [2048..2079]
  //                          lrow [2112..2367]; lx [2368..2623]; lh [2624..2879]
  __shared__ __align__(16) f64 pool[8704];
  __shared__ f64 lds_m[RPB], lds_sd[RPB];
  __shared__ f64 red[WPB];

  const int tid = threadIdx.x, wave = tid>>6, h = tid&63;
  const int bid = blockIdx.x;
  const int batch = bid>>8;              // 256 blocks per batch
  const int nloc = (bid&255)*RPB;
  const long gr0 = (long)batch*NNODES + nloc;
  const int y = wave;                    // tail row (waves 0..3)
  const long gry = gr0 + y;

  // batch max of s_src (exact row max via monotonicity; max is order-exact)
  const f64* sb = ss_in + (long)batch*NNODES;
  f64 mx = -1e300;
  for(int j=tid;j<NNODES;j+=NTHR) mx = fmax(mx, sb[j]);
#pragma unroll
  for(int o=32;o>0;o>>=1) mx = fmax(mx, __shfl_xor(mx,o));
  if(h==0) red[wave]=mx;
  __syncthreads();
  f64 maxS = fmax(fmax(fmax(red[0],red[1]),fmax(red[2],red[3])),
                  fmax(fmax(red[4],red[5]),fmax(red[6],red[7])));
  if(tid<RPB){
    f64 sd = sd_in[gr0+tid];
    lds_sd[tid]=sd;
    f64 v = maxS + sd;
    lds_m[tid] = (v>=0.0)? v : 0.01*v;
  }
  __syncthreads();

  f64 acc0=0.0, acc1=0.0, acc2=0.0, acc3=0.0;  // rows 0..3, this wave's eighth
  f64 wsk=0.0;                                 // lane partial: row h>>4

  const f64* hbase = h1_in + (long)batch*NNODES*HDIM;
  const int t0 = bid & (TPW-1);                // tile rotation within eighth
  f64* wt = pool + wave*1024;                  // wave tile: [16 j][64 h]
  f64* wr = pool + 8192 + wave*64;             // wave weights: [4 rows][16 jj]
  const int wrow = h >> 4, wjj = h & 15;

  // prologue: load tile t0
  double2 r[8]; f64 sval;
  {
    const int j0 = wave*128 + t0*16;
    const double2* src = (const double2*)(hbase + (long)j0*HDIM);
#pragma unroll
    for(int q=0;q<8;q++) r[q] = src[h + q*64];
    sval = sb[j0 + wjj];
  }

  for(int k=0;k<TPW;k++){
    // commit tile k to LDS (waits only this wave's r-loads via vmcnt)
#pragma unroll
    for(int q=0;q<8;q++) ((double2*)wt)[h + q*64] = r[q];
    // issue next tile's loads into rn (stay in flight under FMA)
    double2 rn[8]; f64 snext = 0.0;
    if(k<TPW-1){
      const int jn = (t0 + k + 1) & (TPW-1);
      const int j0n = wave*128 + jn*16;
      const double2* s2 = (const double2*)(hbase + (long)j0n*HDIM);
#pragma unroll
      for(int q=0;q<8;q++) rn[q] = s2[h + q*64];
      snext = sb[j0n + wjj];
    }
    // weights for tile k (exact per-element op order)
    {
      f64 v = sval + lds_sd[wrow];
      v = (v>=0.0)? v : 0.01*v;
      f64 e = exp(v - lds_m[wrow]);
      wr[h] = e;
      wsk += e;
    }
    asm volatile("s_waitcnt lgkmcnt(0)" ::: "memory");  // LDS only; globals in flight
    // FMA over tile k: 4 rows share each data read
#pragma unroll
    for(int p=0;p<8;p++){
      f64 d0 = wt[(2*p)*64 + h];
      f64 d1 = wt[(2*p+1)*64 + h];
      double2 w0 = *(const double2*)(wr      + 2*p);
      double2 w1 = *(const double2*)(wr + 16 + 2*p);
      double2 w2 = *(const double2*)(wr + 32 + 2*p);
      double2 w3 = *(const double2*)(wr + 48 + 2*p);
      acc0 = fma(w0.x,d0,acc0); acc0 = fma(w0.y,d1,acc0);
      acc1 = fma(w1.x,d0,acc1); acc1 = fma(w1.y,d1,acc1);
      acc2 = fma(w2.x,d0,acc2); acc2 = fma(w2.y,d1,acc2);
      acc3 = fma(w3.x,d0,acc3); acc3 = fma(w3.y,d1,acc3);
    }
#pragma unroll
    for(int q=0;q<8;q++) r[q] = rn[q];
    sval = snext;
  }
  // ws: reduce lane partials within 16-lane (jj) groups -> per-row sums
#pragma unroll
  for(int o=1;o<16;o<<=1) wsk += __shfl_xor(wsk, o);
  __syncthreads();   // all waves done with tiles; re-alias pool
  pool[(wave*4+0)*64+h]=acc0;
  pool[(wave*4+1)*64+h]=acc1;
  pool[(wave*4+2)*64+h]=acc2;
  pool[(wave*4+3)*64+h]=acc3;
  if(wjj==0) pool[2048 + wave*4 + wrow] = wsk;
  __syncthreads();

  f64* lrow = pool + 2112;
  f64* lx   = pool + 2368;
  f64* lh   = pool + 2624;

  f64 outv = 0.0;
  if(wave<RPB){
    // combine (fixed order q0->q7); wave w owns row y=w
    f64 a = pool[(0*4+y)*64+h];
#pragma unroll
    for(int q=1;q<WPB;q++) a += pool[(q*4+y)*64+h];
    f64 wsum = pool[2048+0*4+y];
#pragma unroll
    for(int q=1;q<WPB;q++) wsum += pool[2048+q*4+y];
    outv = a/wsum + h1_in[gry*HDIM + h];
    lrow[y*64+h]=outv;
    if(M==0) h1_out[gry*HDIM+h]=outv;
  }
  __syncthreads();

  if(M==0){
    if(wave<RPB){
      f64 s1,s2;
      s_twostage64(lrow+y*64, g_tr_w,g_tr_b,g_a, h, s1,s2);
      if(h==0){ ss_out[gry]=s1; sd_out[gry]=s2; }
    }
  } else {
    const bool hasxi = (step>0);
    if(wave<RPB && hasxi){
      const float* xp = x + ((long)(batch*32+step)*1024 + nloc+y)*6;
      f64 xa = (f64)fb[h];
#pragma unroll
      for(int f=0;f<6;f++) xa += (f64)xp[f]*(f64)fw[f*HDIM+h];
      lx[y*64+h]=xa;
    }
    __syncthreads();
    if(wave<RPB){
      // GRU (same c-order as absmax-0 lineage)
      f64 gi0=(f64)b_ih[h], gi1=(f64)b_ih[64+h], gi2=(f64)b_ih[128+h];
      f64 gh0=(f64)b_hh[h], gh1=(f64)b_hh[64+h], gh2=(f64)b_hh[128+h];
      for(int c=0;c<HDIM;c++){
        f64 o = lrow[y*64+c];
        f64 in = hasxi ? lx[y*64+c] : o;
        gi0 += in*w_ihT[c*192+h]; gi1 += in*w_ihT[c*192+64+h]; gi2 += in*w_ihT[c*192+128+h];
        if(hasxi){
          gh0 += o*w_hhT[c*192+h]; gh1 += o*w_hhT[c*192+64+h]; gh2 += o*w_hhT[c*192+128+h];
        }
      }
      f64 rr = 1.0/(1.0+exp(-(gi0+gh0)));
      f64 zz = 1.0/(1.0+exp(-(gi1+gh1)));
      f64 nn = tanh(gi2 + rr*gh2);
      f64 hn = hasxi ? ((1.0-zz)*nn + zz*outv) : (1.0-zz)*nn;
      lh[y*64+h] = hn;
    }
    __syncthreads();
    if(!is_final){
      if(wave<RPB){
        f64 a1 = (f64)g_in_b[h];
        for(int c=0;c<HDIM;c++) a1 += lh[y*64+c]*(f64)g_in_w[c*HDIM+h];
        h1_out[gry*HDIM+h]=a1;
        lx[y*64+h]=a1;
      }
      __syncthreads();
      if(wave<RPB){
        f64 s1,s2;
        s_twostage64(lx+y*64, g_tr_w,g_tr_b,g_a, h, s1,s2);
        if(h==0){ ss_out[gry]=s1; sd_out[gry]=s2; }
      }
    } else {
      if(wave<RPB){
        f64 hid = (f64)ffn_b[h];
        for(int c=0;c<HDIM;c++) hid += lh[y*64+c]*(f64)ffn_w[c*HDIM+h];
        hid = (hid>=0.0)? hid : 0.01*hid;
        f64 o2 = wredsum64(hid*(f64)ffn_ow[h]);
        if(h==0) out[gry] = (float)(o2 + (f64)ffn_ob[0]);
      }
    }
  }
}

extern "C" void kernel_launch(void* const* d_in, const int* in_sizes, int n_in,
                              void* d_out, int out_size, void* d_ws, size_t ws_size,
                              hipStream_t stream){
  const float* x      = (const float*)d_in[0];
  const float* fc_in_w= (const float*)d_in[1];
  const float* fc_in_b= (const float*)d_in[2];
  const float* g_in_w = (const float*)d_in[3];
  const float* g_in_b = (const float*)d_in[4];
  const float* g_tr_w = (const float*)d_in[5];
  const float* g_tr_b = (const float*)d_in[6];
  const float* g_a    = (const float*)d_in[7];
  const float* w_ih   = (const float*)d_in[8];
  const float* w_hh   = (const float*)d_in[9];
  const float* b_ih   = (const float*)d_in[10];
  const float* b_hh   = (const float*)d_in[11];
  const float* ffn_w  = (const float*)d_in[12];
  const float* ffn_b  = (const float*)d_in[13];
  const float* ffn_ow = (const float*)d_in[14];
  const float* ffn_ob = (const float*)d_in[15];

  f64* h1a   = (f64*)d_ws;
  f64* h1b   = h1a + (long)NROWS*HDIM;
  f64* ssa   = h1b + (long)NROWS*HDIM;
  f64* sda   = ssa + NROWS;
  f64* ssb   = sda + NROWS;
  f64* sdb   = ssb + NROWS;
  f64* w_ihT = sdb + NROWS;
  f64* w_hhT = w_ihT + 192*HDIM;

  float* dout = (float*)d_out;

  k1<<<NROWS/4,256,0,stream>>>(x, fc_in_w, fc_in_b, g_in_w,g_in_b,
                               g_tr_w,g_tr_b,g_a, w_ih,w_hh, w_ihT,w_hhT,
                               h1a,ssa,sda);

  for(int s=0;s<31;s++){
    k_att<0><<<NBLK,NTHR,0,stream>>>(h1a,ssa,sda, h1b,ssb,sdb,
                                     g_tr_w,g_tr_b,g_a,
                                     x,fc_in_w,fc_in_b,
                                     w_ihT,w_hhT,b_ih,b_hh,
                                     g_in_w,g_in_b,
                                     ffn_w,ffn_b,ffn_ow,ffn_ob,
                                     dout, s, 0);
    k_att<1><<<NBLK,NTHR,0,stream>>>(h1b,ssb,sdb, h1a,ssa,sda,
                                     g_tr_w,g_tr_b,g_a,
                                     x,fc_in_w,fc_in_b,
                                     w_ihT,w_hhT,b_ih,b_hh,
                                     g_in_w,g_in_b,
                                     ffn_w,ffn_b,ffn_ow,ffn_ob,
                                     dout, s, (s==30)?1:0);
  }
}

// Round 18
// 2838.801 us; speedup vs baseline: 1.8664x; 1.8664x over previous
//
#include <hip/hip_runtime.h>
#include <math.h>

typedef double f64;
#define HDIM 64
#define NNODES 1024
#define NROWS 2048
#define RPB 32              // rows per kAgg block
#define NCH 16              // j-chunks
#define CHJ (NNODES/NCH)    // 64 j per chunk

__device__ __forceinline__ f64 wredsum64(f64 v){
#pragma unroll
  for(int o=32;o>0;o>>=1) v += __shfl_xor(v,o);
  return v;
}

// two-stage score, same op-order as the absmax-0 lineage
__device__ __forceinline__ void s_twostage64(const f64* __restrict__ ldsrow,
    const float* __restrict__ g_tr_w, const float* __restrict__ g_tr_b,
    const float* __restrict__ g_a, int h, f64& s_src, f64& s_dst){
  f64 t = (f64)g_tr_b[h];
  for(int c=0;c<HDIM;c++) t = fma(ldsrow[c], (f64)g_tr_w[c*HDIM+h], t);
  s_src = wredsum64(t*(f64)g_a[h]);
  s_dst = wredsum64(t*(f64)g_a[HDIM+h]);
}

// parallel f64 transpose of GRU weights
__global__ void k_pre(const float* __restrict__ w_ih, const float* __restrict__ w_hh,
                      f64* __restrict__ w_ihT, f64* __restrict__ w_hhT){
  int k = blockIdx.x*256 + threadIdx.x;
  if(k >= 192*HDIM) return;
  int row=k>>6, c=k&63;
  w_ihT[c*192+row]=(f64)w_ih[k];
  w_hhT[c*192+row]=(f64)w_hh[k];
}

// initial h1 + scores. 1 wave/row.
__global__ void k1(const float* __restrict__ x, const float* __restrict__ fw,
                   const float* __restrict__ fb,
                   const float* __restrict__ g_in_w, const float* __restrict__ g_in_b,
                   const float* __restrict__ g_tr_w, const float* __restrict__ g_tr_b,
                   const float* __restrict__ g_a,
                   f64* __restrict__ h1, f64* __restrict__ ssrc, f64* __restrict__ sdst){
  __shared__ f64 lx[4*64];
  __shared__ f64 lt[4*64];
  int wave = threadIdx.x >> 6, h = threadIdx.x & 63;
  int r = blockIdx.x*4 + wave;
  int b = r >> 10, n = r & 1023;
  const float* xp = x + ((long)(b*32 + 0)*1024 + n)*6;
  f64 xh = (f64)fb[h];
#pragma unroll
  for(int f=0;f<6;f++) xh += (f64)xp[f]*(f64)fw[f*HDIM+h];
  lx[wave*64+h] = xh;
  __syncthreads();
  f64 a = (f64)g_in_b[h];
  for(int c=0;c<HDIM;c++) a += lx[wave*64+c]*(f64)g_in_w[c*HDIM+h];
  h1[(long)r*HDIM+h] = a;
  lt[wave*64+h] = a;
  __syncthreads();
  f64 s1,s2;
  s_twostage64(lt+wave*64, g_tr_w,g_tr_b,g_a, h, s1,s2);
  if(h==0){ ssrc[r]=s1; sdst[r]=s2; }
}

// Partial attention aggregation. grid = (NROWS/RPB)*NCH = 1024 blocks x 512 thr.
// Block (rg, chunk): 32 rows, j in [chunk*64, +64). One 32KB tile. 2 blocks/CU.
__global__ __launch_bounds__(512) void kAgg(
    const f64* __restrict__ h1_in, const f64* __restrict__ ss_in,
    const f64* __restrict__ sd_in,
    f64* __restrict__ pacc, f64* __restrict__ pws)
{
  __shared__ __align__(16) f64 htile[64*64];  // 32 KB
  __shared__ __align__(16) f64 wbuf[RPB*64];  // 16 KB
  __shared__ f64 lds_m[RPB];
  __shared__ f64 lds_sd[RPB];
  __shared__ f64 red[8];

  const int tid = threadIdx.x, wave = tid>>6, h = tid&63;
  const int chunk = blockIdx.x & (NCH-1);
  const int rg = blockIdx.x >> 4;           // 0..63 (32 rows each)
  const int batch = rg >> 5;                // 32 rgs/batch
  const long gr0 = (long)batch*NNODES + (long)(rg & 31)*RPB;

  const f64* sb = ss_in + (long)batch*NNODES;
  // batch max of s_src (exact row max via monotonicity)
  f64 mx = -1e300;
  for(int j=tid;j<NNODES;j+=512) mx = fmax(mx, sb[j]);
#pragma unroll
  for(int o=32;o>0;o>>=1) mx = fmax(mx, __shfl_xor(mx,o));
  if(h==0) red[wave]=mx;
  __syncthreads();
  f64 maxS = fmax(fmax(fmax(red[0],red[1]),fmax(red[2],red[3])),
                  fmax(fmax(red[4],red[5]),fmax(red[6],red[7])));
  if(tid<RPB){
    f64 sd = sd_in[gr0+tid];
    lds_sd[tid]=sd;
    f64 v = maxS + sd;
    lds_m[tid] = (v>=0.0)? v : 0.01*v;
  }
  __syncthreads();

  f64 acc0=0.0, acc1=0.0, acc2=0.0, acc3=0.0;   // FMA rows wave*4+0..3
  f64 wsk0=0.0, wsk1=0.0, wsk2=0.0, wsk3=0.0;   // ws lane-partials rows wave+8k

  {
    const int j0 = chunk*CHJ;
    const f64* src = h1_in + ((long)batch*NNODES + j0)*HDIM;
#pragma unroll
    for(int k=0;k<4;k++){
      int idx = tid + k*512;   // 2048 double2 slots
      ((double2*)htile)[idx] = ((const double2*)src)[idx];
    }
    // W build: entry idx = row*64+jj ; thread covers rows wave+8k (exact op order)
#pragma unroll
    for(int k=0;k<4;k++){
      int idx = tid + k*512;
      int row = idx>>6, jj = idx&63;
      f64 v = sb[j0+jj] + lds_sd[row];
      v = (v>=0.0)? v : 0.01*v;
      f64 e = exp(v - lds_m[row]);
      wbuf[idx] = e;
      if(k==0) wsk0+=e; else if(k==1) wsk1+=e; else if(k==2) wsk2+=e; else wsk3+=e;
    }
    __syncthreads();
    const f64* wb = wbuf + (wave*4)*64;
#pragma unroll 4
    for(int jg=0; jg<16; jg++){
      int base = jg*4*64 + h;
      f64 h0 = htile[base], h1v = htile[base+64];
      f64 h2 = htile[base+128], h3 = htile[base+192];
      double2 wa  = *(const double2*)(wb + jg*4);
      double2 wa2 = *(const double2*)(wb + jg*4 + 2);
      double2 wbv = *(const double2*)(wb + 64 + jg*4);
      double2 wb2 = *(const double2*)(wb + 64 + jg*4 + 2);
      double2 wc  = *(const double2*)(wb + 128 + jg*4);
      double2 wc2 = *(const double2*)(wb + 128 + jg*4 + 2);
      double2 wd  = *(const double2*)(wb + 192 + jg*4);
      double2 wd2 = *(const double2*)(wb + 192 + jg*4 + 2);
      acc0 = fma(wa.x,h0,acc0);  acc0 = fma(wa.y,h1v,acc0);
      acc0 = fma(wa2.x,h2,acc0); acc0 = fma(wa2.y,h3,acc0);
      acc1 = fma(wbv.x,h0,acc1); acc1 = fma(wbv.y,h1v,acc1);
      acc1 = fma(wb2.x,h2,acc1); acc1 = fma(wb2.y,h3,acc1);
      acc2 = fma(wc.x,h0,acc2);  acc2 = fma(wc.y,h1v,acc2);
      acc2 = fma(wc2.x,h2,acc2); acc2 = fma(wc2.y,h3,acc2);
      acc3 = fma(wd.x,h0,acc3);  acc3 = fma(wd.y,h1v,acc3);
      acc3 = fma(wd2.x,h2,acc3); acc3 = fma(wd2.y,h3,acc3);
    }
  }

  const long pbase = (long)chunk*NROWS + gr0;
  pacc[(pbase + wave*4+0)*HDIM + h] = acc0;
  pacc[(pbase + wave*4+1)*HDIM + h] = acc1;
  pacc[(pbase + wave*4+2)*HDIM + h] = acc2;
  pacc[(pbase + wave*4+3)*HDIM + h] = acc3;
  f64 w0 = wredsum64(wsk0), w1 = wredsum64(wsk1);
  f64 w2 = wredsum64(wsk2), w3 = wredsum64(wsk3);
  if(h==0){
    pws[pbase + wave     ] = w0;
    pws[pbase + wave + 8 ] = w1;
    pws[pbase + wave + 16] = w2;
    pws[pbase + wave + 24] = w3;
  }
}

// Combine partials -> gat-iter output + residual; then scores. 1 wave/row.
__global__ void kFin0(const f64* __restrict__ pacc, const f64* __restrict__ pws,
                      const f64* __restrict__ h1_in,
                      const float* __restrict__ g_tr_w, const float* __restrict__ g_tr_b,
                      const float* __restrict__ g_a,
                      f64* __restrict__ h1_out, f64* __restrict__ ss_out, f64* __restrict__ sd_out){
  __shared__ f64 lt[4*64];
  int wave = threadIdx.x>>6, h = threadIdx.x&63;
  long r = blockIdx.x*4 + wave;
  f64 a = 0.0, w = 0.0;
#pragma unroll
  for(int c=0;c<NCH;c++){
    a += pacc[((long)c*NROWS + r)*HDIM + h];
    w += pws[(long)c*NROWS + r];
  }
  f64 out = a/w + h1_in[r*HDIM+h];
  h1_out[r*HDIM+h] = out;
  lt[wave*64+h] = out;
  __syncthreads();
  f64 s1,s2;
  s_twostage64(lt+wave*64, g_tr_w,g_tr_b,g_a, h, s1,s2);
  if(h==0){ ss_out[r]=s1; sd_out[r]=s2; }
}

// Combine -> gat out; GRU; then next h1+scores or FFN head. 1 wave/row.
__global__ void kFin1(const f64* __restrict__ pacc, const f64* __restrict__ pws,
                      const f64* __restrict__ h1_in,
                      const float* __restrict__ x, const float* __restrict__ fw,
                      const float* __restrict__ fb,
                      const f64* __restrict__ w_ihT, const f64* __restrict__ w_hhT,
                      const float* __restrict__ b_ih, const float* __restrict__ b_hh,
                      const float* __restrict__ g_in_w, const float* __restrict__ g_in_b,
                      const float* __restrict__ g_tr_w, const float* __restrict__ g_tr_b,
                      const float* __restrict__ g_a,
                      const float* __restrict__ ffn_w, const float* __restrict__ ffn_b,
                      const float* __restrict__ ffn_ow, const float* __restrict__ ffn_ob,
                      f64* __restrict__ h1_out, f64* __restrict__ ss_out, f64* __restrict__ sd_out,
                      float* __restrict__ out, int step, int is_final){
  __shared__ f64 lo[4*64];
  __shared__ f64 lx[4*64];
  __shared__ f64 lh[4*64];
  int wave = threadIdx.x>>6, h = threadIdx.x&63;
  long r = blockIdx.x*4 + wave;
  int batch = (int)(r>>10), n = (int)(r&1023);
  f64 a = 0.0, w = 0.0;
#pragma unroll
  for(int c=0;c<NCH;c++){
    a += pacc[((long)c*NROWS + r)*HDIM + h];
    w += pws[(long)c*NROWS + r];
  }
  f64 gato = a/w + h1_in[r*HDIM+h];
  lo[wave*64+h] = gato;
  const bool hasxi = (step>0);
  if(hasxi){
    const float* xp = x + ((long)(batch*32 + step)*1024 + n)*6;
    f64 xi = (f64)fb[h];
#pragma unroll
    for(int f=0;f<6;f++) xi += (f64)xp[f]*(f64)fw[f*HDIM+h];
    lx[wave*64+h] = xi;
  }
  __syncthreads();
  f64 gi0=(f64)b_ih[h], gi1=(f64)b_ih[64+h], gi2=(f64)b_ih[128+h];
  f64 gh0=(f64)b_hh[h], gh1=(f64)b_hh[64+h], gh2=(f64)b_hh[128+h];
  for(int c=0;c<HDIM;c++){
    f64 o = lo[wave*64+c];
    f64 in = hasxi ? lx[wave*64+c] : o;
    gi0 += in*w_ihT[c*192+h]; gi1 += in*w_ihT[c*192+64+h]; gi2 += in*w_ihT[c*192+128+h];
    if(hasxi){
      gh0 += o*w_hhT[c*192+h]; gh1 += o*w_hhT[c*192+64+h]; gh2 += o*w_hhT[c*192+128+h];
    }
  }
  f64 rr = 1.0/(1.0+exp(-(gi0+gh0)));
  f64 zz = 1.0/(1.0+exp(-(gi1+gh1)));
  f64 nn = tanh(gi2 + rr*gh2);
  f64 hn = hasxi ? ((1.0-zz)*nn + zz*gato) : (1.0-zz)*nn;
  lh[wave*64+h] = hn;
  __syncthreads();
  if(!is_final){
    f64 a1 = (f64)g_in_b[h];
    for(int c=0;c<HDIM;c++) a1 += lh[wave*64+c]*(f64)g_in_w[c*HDIM+h];
    h1_out[r*HDIM+h] = a1;
    lx[wave*64+h] = a1;
    __syncthreads();
    f64 s1,s2;
    s_twostage64(lx+wave*64, g_tr_w,g_tr_b,g_a, h, s1,s2);
    if(h==0){ ss_out[r]=s1; sd_out[r]=s2; }
  } else {
    f64 hid = (f64)ffn_b[h];
    for(int c=0;c<HDIM;c++) hid += lh[wave*64+c]*(f64)ffn_w[c*HDIM+h];
    hid = (hid>=0.0)? hid : 0.01*hid;
    f64 o2 = wredsum64(hid*(f64)ffn_ow[h]);
    if(h==0) out[r] = (float)(o2 + (f64)ffn_ob[0]);
  }
}

extern "C" void kernel_launch(void* const* d_in, const int* in_sizes, int n_in,
                              void* d_out, int out_size, void* d_ws, size_t ws_size,
                              hipStream_t stream){
  const float* x      = (const float*)d_in[0];
  const float* fc_in_w= (const float*)d_in[1];
  const float* fc_in_b= (const float*)d_in[2];
  const float* g_in_w = (const float*)d_in[3];
  const float* g_in_b = (const float*)d_in[4];
  const float* g_tr_w = (const float*)d_in[5];
  const float* g_tr_b = (const float*)d_in[6];
  const float* g_a    = (const float*)d_in[7];
  const float* w_ih   = (const float*)d_in[8];
  const float* w_hh   = (const float*)d_in[9];
  const float* b_ih   = (const float*)d_in[10];
  const float* b_hh   = (const float*)d_in[11];
  const float* ffn_w  = (const float*)d_in[12];
  const float* ffn_b  = (const float*)d_in[13];
  const float* ffn_ow = (const float*)d_in[14];
  const float* ffn_ob = (const float*)d_in[15];

  f64* h1a   = (f64*)d_ws;
  f64* h1b   = h1a + (long)NROWS*HDIM;
  f64* ssa   = h1b + (long)NROWS*HDIM;
  f64* sda   = ssa + NROWS;
  f64* ssb   = sda + NROWS;
  f64* sdb   = ssb + NROWS;
  f64* w_ihT = sdb + NROWS;
  f64* w_hhT = w_ihT + 192*HDIM;
  f64* pacc  = w_hhT + 192*HDIM;              // 16*2048*64 f64 = 16 MB
  f64* pws   = pacc + (long)NCH*NROWS*HDIM;   // 16*2048

  float* dout = (float*)d_out;

  k_pre<<<48,256,0,stream>>>(w_ih,w_hh,w_ihT,w_hhT);
  k1<<<NROWS/4,256,0,stream>>>(x, fc_in_w, fc_in_b, g_in_w,g_in_b,
                               g_tr_w,g_tr_b,g_a, h1a,ssa,sda);

  for(int s=0;s<31;s++){
    kAgg<<<(NROWS/RPB)*NCH,512,0,stream>>>(h1a,ssa,sda, pacc,pws);
    kFin0<<<NROWS/4,256,0,stream>>>(pacc,pws,h1a, g_tr_w,g_tr_b,g_a, h1b,ssb,sdb);
    kAgg<<<(NROWS/RPB)*NCH,512,0,stream>>>(h1b,ssb,sdb, pacc,pws);
    kFin1<<<NROWS/4,256,0,stream>>>(pacc,pws,h1b,
                                    x,fc_in_w,fc_in_b,
                                    w_ihT,w_hhT,b_ih,b_hh,
                                    g_in_w,g_in_b, g_tr_w,g_tr_b,g_a,
                                    ffn_w,ffn_b,ffn_ow,ffn_ob,
                                    h1a,ssa,sda, dout, s, (s==30)?1:0);
  }
}